// Round 10
// baseline (960.047 us; speedup 1.0000x reference)
//
#include <hip/hip_runtime.h>
#include <hip/hip_bf16.h>

#define NN 100000
#define EE 1600000

typedef __attribute__((ext_vector_type(8))) short short8;
typedef __attribute__((ext_vector_type(4))) float f32x4;

__device__ __forceinline__ unsigned short f2bfu(float f) {
    __hip_bfloat16 h = __float2bfloat16(f);
    return *reinterpret_cast<unsigned short*>(&h);
}
__device__ __forceinline__ float bf2f(unsigned short u) {
    return __uint_as_float((unsigned int)u << 16);
}

// ---------------- workspace layout (bytes) ----------------
// WCT 0 (49152) | BC 49152 | Z0 65536 (12.8e6) | ZA 12865536 | ZB 25665536
// DINV 38465536 | CNT 38865536 | PTR 39265536 | BSUM 39665664 | PTR2 39667712
// CEV 40067840 (12.8e6) | PERM 52867840 (400000) | HIST 53267840 (1024)
// total ~53.3 MB   (z rows padded to 64 bf16 = one 128B line)

__global__ void wct_kernel(const float* __restrict__ W1, const float* __restrict__ W2,
                           const float* __restrict__ b1, short* __restrict__ WcT,
                           float* __restrict__ bc) {
    int t = blockIdx.x * 256 + threadIdx.x;
    if (t < 48 * 512) {
        int j = t >> 9, k = t & 511;
        float s = 0.f;
        if (j < 40)
            for (int i = 0; i < 128; ++i) s = fmaf(W1[k * 128 + i], W2[i * 40 + j], s);
        WcT[j * 512 + k] = (short)f2bfu(s);
    } else if (t < 48 * 512 + 48) {
        int j = t - 48 * 512;
        float s = 0.f;
        if (j < 40)
            for (int i = 0; i < 128; ++i) s = fmaf(b1[i], W2[i * 40 + j], s);
        bc[j] = s;
    }
}

// z0 = bf16( x @ Wc + bc ), rows padded to 64 (cols 40..47 zeros via WcT pad, 48..63 explicit 0)
__global__ __launch_bounds__(256) void gemm_z0(const float* __restrict__ x,
                                               const short* __restrict__ WcT,
                                               const float* __restrict__ bc,
                                               unsigned short* __restrict__ z0) {
    const int tid = threadIdx.x;
    const int lane = tid & 63;
    const int wave = tid >> 6;
    const int rbase = blockIdx.x * 64 + wave * 16;
    const int row = rbase + (lane & 15);
    const int kc = lane >> 4;
    const bool rok = row < NN;

    f32x4 acc0 = {0.f, 0.f, 0.f, 0.f};
    f32x4 acc1 = {0.f, 0.f, 0.f, 0.f};
    f32x4 acc2 = {0.f, 0.f, 0.f, 0.f};

    const float* xrow = x + (size_t)row * 512 + kc * 8;
    const short* bp0 = WcT + (size_t)(lane & 15) * 512 + kc * 8;
    const short* bp1 = bp0 + 16 * 512;
    const short* bp2 = bp0 + 32 * 512;

    for (int k0 = 0; k0 < 512; k0 += 32) {
        float4 p0 = {0.f, 0.f, 0.f, 0.f}, p1 = {0.f, 0.f, 0.f, 0.f};
        if (rok) {
            p0 = *reinterpret_cast<const float4*>(xrow + k0);
            p1 = *reinterpret_cast<const float4*>(xrow + k0 + 4);
        }
        short8 a;
        a[0] = (short)f2bfu(p0.x); a[1] = (short)f2bfu(p0.y);
        a[2] = (short)f2bfu(p0.z); a[3] = (short)f2bfu(p0.w);
        a[4] = (short)f2bfu(p1.x); a[5] = (short)f2bfu(p1.y);
        a[6] = (short)f2bfu(p1.z); a[7] = (short)f2bfu(p1.w);
        short8 b0 = *reinterpret_cast<const short8*>(bp0 + k0);
        short8 b1 = *reinterpret_cast<const short8*>(bp1 + k0);
        short8 b2 = *reinterpret_cast<const short8*>(bp2 + k0);
        acc0 = __builtin_amdgcn_mfma_f32_16x16x32_bf16(a, b0, acc0, 0, 0, 0);
        acc1 = __builtin_amdgcn_mfma_f32_16x16x32_bf16(a, b1, acc1, 0, 0, 0);
        acc2 = __builtin_amdgcn_mfma_f32_16x16x32_bf16(a, b2, acc2, 0, 0, 0);
    }

    const int cb = lane & 15;
    const int rr = rbase + (lane >> 4) * 4;
#pragma unroll
    for (int q = 0; q < 4; ++q) {
        int r = rr + q;
        if (r < NN) {
            z0[(size_t)r * 64 + cb] = f2bfu(acc0[q] + bc[cb]);
            z0[(size_t)r * 64 + cb + 16] = f2bfu(acc1[q] + bc[cb + 16]);
            z0[(size_t)r * 64 + cb + 32] = f2bfu(acc2[q] + bc[cb + 32]);
            z0[(size_t)r * 64 + cb + 48] = 0;
        }
    }
}

__global__ void count_kernel(const int* __restrict__ eidx, int* __restrict__ counts) {
    int e = blockIdx.x * 256 + threadIdx.x;
    if (e < EE) atomicAdd(&counts[eidx[EE + e]], 1);
}

__global__ void scan1(const int* __restrict__ counts, int* __restrict__ ptr,
                      int* __restrict__ bsum) {
    __shared__ int s[256];
    int tid = threadIdx.x;
    int i = blockIdx.x * 256 + tid;
    int v = (i < NN) ? counts[i] : 0;
    s[tid] = v;
    __syncthreads();
    for (int off = 1; off < 256; off <<= 1) {
        int t = (tid >= off) ? s[tid - off] : 0;
        __syncthreads();
        s[tid] += t;
        __syncthreads();
    }
    if (i < NN) ptr[i] = s[tid] - v;
    if (tid == 255) bsum[blockIdx.x] = s[255];
}

__global__ void scan2(int* __restrict__ bsum) {
    __shared__ int s[512];
    int tid = threadIdx.x;
    int v = (tid < 391) ? bsum[tid] : 0;
    s[tid] = v;
    __syncthreads();
    for (int off = 1; off < 512; off <<= 1) {
        int t = (tid >= off) ? s[tid - off] : 0;
        __syncthreads();
        s[tid] += t;
        __syncthreads();
    }
    if (tid < 391) bsum[tid] = s[tid] - v;
}

__global__ void scan3(int* __restrict__ ptr, const int* __restrict__ bsum,
                      const int* __restrict__ counts, float* __restrict__ dinvp,
                      int* __restrict__ ptr2) {
    int i = blockIdx.x * 256 + threadIdx.x;
    if (i < NN) {
        int p = ptr[i] + bsum[blockIdx.x];
        ptr[i] = p;
        ptr2[i] = p;
        dinvp[i] = rsqrtf(1.0f + (float)counts[i]);
    }
    if (i == 0) { ptr[NN] = EE; ptr2[NN] = EE; }
}

// ---- degree-matched pairing: 256-bin counting sort of nodes by in-degree ----
__global__ void hist_kernel(const int* __restrict__ counts, int* __restrict__ hist) {
    int i = blockIdx.x * 256 + threadIdx.x;
    if (i < NN) {
        int b = counts[i]; if (b > 255) b = 255;
        atomicAdd(&hist[b], 1);
    }
}

__global__ void hscan_kernel(int* __restrict__ hist) {  // exclusive scan of 256
    __shared__ int s[256];
    int tid = threadIdx.x;
    int v = hist[tid];
    s[tid] = v;
    __syncthreads();
    for (int off = 1; off < 256; off <<= 1) {
        int t = (tid >= off) ? s[tid - off] : 0;
        __syncthreads();
        s[tid] += t;
        __syncthreads();
    }
    hist[tid] = s[tid] - v;
}

__global__ void place_kernel(const int* __restrict__ counts, int* __restrict__ hist,
                             int* __restrict__ perm) {
    int i = blockIdx.x * 256 + threadIdx.x;
    if (i < NN) {
        int b = counts[i]; if (b > 255) b = 255;
        int pos = atomicAdd(&hist[b], 1);
        perm[pos] = i;
    }
}

__global__ void scatter_kernel(const int* __restrict__ eidx,
                               const float* __restrict__ dinvp, int* __restrict__ ptr2,
                               int2* __restrict__ cev) {
    int e = blockIdx.x * 256 + threadIdx.x;
    if (e < EE) {
        int r = eidx[e];
        int c = eidx[EE + e];
        int pos = atomicAdd(&ptr2[c], 1);
        cev[pos] = make_int2(r, __float_as_int(dinvp[r]));
    }
}

// 2 degree-matched nodes per wave; branch-free chunks of 8 edges per node,
// 16 gathers in flight; 32-bit gather offsets; 8 waves/SIMD pinned.
__global__ __launch_bounds__(256, 8) void propagate(const unsigned short* __restrict__ zcur,
                                                    const unsigned short* __restrict__ z0q,
                                                    unsigned short* __restrict__ znb,
                                                    float* __restrict__ outf,
                                                    const int* __restrict__ ptr,
                                                    const int2* __restrict__ cev,
                                                    const float* __restrict__ dinvp,
                                                    const float* __restrict__ b2,
                                                    const int* __restrict__ perm, int last) {
    const int lane = threadIdx.x & 63;
    const int wid = blockIdx.x * 4 + (threadIdx.x >> 6);
    const int n0 = __builtin_amdgcn_readfirstlane(perm[2 * wid]);
    const int n1 = __builtin_amdgcn_readfirstlane(perm[2 * wid + 1]);

    int beg0 = __builtin_amdgcn_readfirstlane(ptr[n0]);
    int end0 = __builtin_amdgcn_readfirstlane(ptr[n0 + 1]);
    int beg1 = __builtin_amdgcn_readfirstlane(ptr[n1]);
    int end1 = __builtin_amdgcn_readfirstlane(ptr[n1 + 1]);
    const float dc0 = dinvp[n0], dc1 = dinvp[n1];

    int m0 = end0 - beg0; if (m0 > 64) m0 = 64;
    int m1 = end1 - beg1; if (m1 > 64) m1 = 64;

    // batch loads: rows clamped to a valid entry, weights zeroed for lanes >= m
    int idx0 = beg0 + (lane < m0 ? lane : m0 - 1); if (idx0 < 0) idx0 = 0;
    int idx1 = beg1 + (lane < m1 ? lane : m1 - 1); if (idx1 < 0) idx1 = 0;
    int2 ev0 = cev[idx0];
    int2 ev1 = cev[idx1];
    if (lane >= m0) ev0.y = 0;
    if (lane >= m1) ev1.y = 0;

    const float self0 = bf2f(zcur[(unsigned)(n0 * 64 + lane)]);
    const float self1 = bf2f(zcur[(unsigned)(n1 * 64 + lane)]);
    const float z00 = bf2f(z0q[(unsigned)(n0 * 64 + lane)]);
    const float z01 = bf2f(z0q[(unsigned)(n1 * 64 + lane)]);

    float A0 = dc0 * self0, B0 = 0.f;
    float A1 = dc1 * self1, B1 = 0.f;

    int nc0 = (m0 + 7) >> 3, nc1 = (m1 + 7) >> 3;
    int nc = nc0 > nc1 ? nc0 : nc1;
    for (int c = 0; c < nc; ++c) {
        const int j = c * 8;
        float x[8], y[8];
#pragma unroll
        for (int k = 0; k < 8; ++k) {
            unsigned r0 = (unsigned)__builtin_amdgcn_readlane(ev0.x, j + k);
            unsigned r1 = (unsigned)__builtin_amdgcn_readlane(ev1.x, j + k);
            x[k] = bf2f(zcur[(r0 << 6) + lane]);
            y[k] = bf2f(zcur[(r1 << 6) + lane]);
        }
#pragma unroll
        for (int k = 0; k < 8; ++k) {
            float w = __int_as_float(__builtin_amdgcn_readlane(ev0.y, j + k));
            float u = __int_as_float(__builtin_amdgcn_readlane(ev1.y, j + k));
            if (k & 1) { B0 = fmaf(w, x[k], B0); B1 = fmaf(u, y[k], B1); }
            else       { A0 = fmaf(w, x[k], A0); A1 = fmaf(u, y[k], A1); }
        }
    }

    // ultra-rare tail: degree > 64
    for (int e = beg0 + 64; e < end0; ++e) {
        int2 ee = cev[e];
        A0 = fmaf(__int_as_float(ee.y), bf2f(zcur[((unsigned)ee.x << 6) + lane]), A0);
    }
    for (int e = beg1 + 64; e < end1; ++e) {
        int2 ee = cev[e];
        A1 = fmaf(__int_as_float(ee.y), bf2f(zcur[((unsigned)ee.x << 6) + lane]), A1);
    }

    float res0 = 0.5f * dc0 * (A0 + B0) + 0.5f * z00;
    float res1 = 0.5f * dc1 * (A1 + B1) + 0.5f * z01;
    if (last) {
        if (lane < 40) {
            outf[(unsigned)(n0 * 40 + lane)] = res0 + b2[lane];
            outf[(unsigned)(n1 * 40 + lane)] = res1 + b2[lane];
        }
    } else {
        znb[(unsigned)(n0 * 64 + lane)] = f2bfu(res0);
        znb[(unsigned)(n1 * 64 + lane)] = f2bfu(res1);
    }
}

extern "C" void kernel_launch(void* const* d_in, const int* in_sizes, int n_in,
                              void* d_out, int out_size, void* d_ws, size_t ws_size,
                              hipStream_t stream) {
    const float* x  = (const float*)d_in[0];
    const int*   ei = (const int*)d_in[1];
    const float* W1 = (const float*)d_in[2];
    const float* b1 = (const float*)d_in[3];
    const float* W2 = (const float*)d_in[4];
    const float* b2 = (const float*)d_in[5];
    float* out = (float*)d_out;

    char* ws = (char*)d_ws;
    short*          WcT  = (short*)(ws + 0);
    float*          bc   = (float*)(ws + 49152);
    unsigned short* z0   = (unsigned short*)(ws + 65536);
    unsigned short* za   = (unsigned short*)(ws + 12865536);
    unsigned short* zb   = (unsigned short*)(ws + 25665536);
    float*          dinv = (float*)(ws + 38465536);
    int*            cnt  = (int*)(ws + 38865536);
    int*            ptr  = (int*)(ws + 39265536);
    int*            bsum = (int*)(ws + 39665664);
    int*            ptr2 = (int*)(ws + 39667712);
    int2*           cev  = (int2*)(ws + 40067840);
    int*            perm = (int*)(ws + 52867840);
    int*            hist = (int*)(ws + 53267840);

    hipMemsetAsync(cnt, 0, NN * sizeof(int), stream);
    hipMemsetAsync(hist, 0, 256 * sizeof(int), stream);
    wct_kernel<<<97, 256, 0, stream>>>(W1, W2, b1, WcT, bc);
    count_kernel<<<(EE + 255) / 256, 256, 0, stream>>>(ei, cnt);
    scan1<<<391, 256, 0, stream>>>(cnt, ptr, bsum);
    scan2<<<1, 512, 0, stream>>>(bsum);
    scan3<<<391, 256, 0, stream>>>(ptr, bsum, cnt, dinv, ptr2);
    hist_kernel<<<391, 256, 0, stream>>>(cnt, hist);
    hscan_kernel<<<1, 256, 0, stream>>>(hist);
    place_kernel<<<391, 256, 0, stream>>>(cnt, hist, perm);
    gemm_z0<<<1563, 256, 0, stream>>>(x, WcT, bc, z0);
    scatter_kernel<<<(EE + 255) / 256, 256, 0, stream>>>(ei, dinv, ptr2, cev);

    propagate<<<12500, 256, 0, stream>>>(z0, z0, zb, out, ptr, cev, dinv, b2, perm, 0);
    propagate<<<12500, 256, 0, stream>>>(zb, z0, za, out, ptr, cev, dinv, b2, perm, 0);
    propagate<<<12500, 256, 0, stream>>>(za, z0, zb, out, ptr, cev, dinv, b2, perm, 0);
    propagate<<<12500, 256, 0, stream>>>(zb, z0, za, out, ptr, cev, dinv, b2, perm, 0);
    propagate<<<12500, 256, 0, stream>>>(za, z0, zb, out, ptr, cev, dinv, b2, perm, 1);
}

// Round 11
// 434.918 us; speedup vs baseline: 2.2074x; 2.2074x over previous
//
#include <hip/hip_runtime.h>
#include <hip/hip_bf16.h>

#define NN 100000
#define EE 1600000
#define HALFN 50000

typedef __attribute__((ext_vector_type(8))) short short8;
typedef __attribute__((ext_vector_type(4))) float f32x4;

__device__ __forceinline__ unsigned short f2bfu(float f) {
    __hip_bfloat16 h = __float2bfloat16(f);
    return *reinterpret_cast<unsigned short*>(&h);
}
__device__ __forceinline__ float bf2f(unsigned short u) {
    return __uint_as_float((unsigned int)u << 16);
}

// ---------------- workspace layout (bytes) ----------------
// WCT 0 (49152) | BC 49152 | Z0 65536 (12.8e6) | ZA 12865536 | ZB 25665536
// DINV 38465536 | CNT 38865536 | PTR 39265536 | BSUM 39665664 | PTR2 39667712
// CEV 40067840 | total ~52.9 MB   (z rows padded to 64 bf16 = one 128B line)

__global__ void wct_kernel(const float* __restrict__ W1, const float* __restrict__ W2,
                           const float* __restrict__ b1, short* __restrict__ WcT,
                           float* __restrict__ bc) {
    int t = blockIdx.x * 256 + threadIdx.x;
    if (t < 48 * 512) {
        int j = t >> 9, k = t & 511;
        float s = 0.f;
        if (j < 40)
            for (int i = 0; i < 128; ++i) s = fmaf(W1[k * 128 + i], W2[i * 40 + j], s);
        WcT[j * 512 + k] = (short)f2bfu(s);
    } else if (t < 48 * 512 + 48) {
        int j = t - 48 * 512;
        float s = 0.f;
        if (j < 40)
            for (int i = 0; i < 128; ++i) s = fmaf(b1[i], W2[i * 40 + j], s);
        bc[j] = s;
    }
}

// z0 = bf16( x @ Wc + bc ), rows padded to 64 (cols 40..47 zeros via WcT pad, 48..63 explicit 0)
__global__ __launch_bounds__(256) void gemm_z0(const float* __restrict__ x,
                                               const short* __restrict__ WcT,
                                               const float* __restrict__ bc,
                                               unsigned short* __restrict__ z0) {
    const int tid = threadIdx.x;
    const int lane = tid & 63;
    const int wave = tid >> 6;
    const int rbase = blockIdx.x * 64 + wave * 16;
    const int row = rbase + (lane & 15);
    const int kc = lane >> 4;
    const bool rok = row < NN;

    f32x4 acc0 = {0.f, 0.f, 0.f, 0.f};
    f32x4 acc1 = {0.f, 0.f, 0.f, 0.f};
    f32x4 acc2 = {0.f, 0.f, 0.f, 0.f};

    const float* xrow = x + (size_t)row * 512 + kc * 8;
    const short* bp0 = WcT + (size_t)(lane & 15) * 512 + kc * 8;
    const short* bp1 = bp0 + 16 * 512;
    const short* bp2 = bp0 + 32 * 512;

    for (int k0 = 0; k0 < 512; k0 += 32) {
        float4 p0 = {0.f, 0.f, 0.f, 0.f}, p1 = {0.f, 0.f, 0.f, 0.f};
        if (rok) {
            p0 = *reinterpret_cast<const float4*>(xrow + k0);
            p1 = *reinterpret_cast<const float4*>(xrow + k0 + 4);
        }
        short8 a;
        a[0] = (short)f2bfu(p0.x); a[1] = (short)f2bfu(p0.y);
        a[2] = (short)f2bfu(p0.z); a[3] = (short)f2bfu(p0.w);
        a[4] = (short)f2bfu(p1.x); a[5] = (short)f2bfu(p1.y);
        a[6] = (short)f2bfu(p1.z); a[7] = (short)f2bfu(p1.w);
        short8 b0 = *reinterpret_cast<const short8*>(bp0 + k0);
        short8 b1 = *reinterpret_cast<const short8*>(bp1 + k0);
        short8 b2 = *reinterpret_cast<const short8*>(bp2 + k0);
        acc0 = __builtin_amdgcn_mfma_f32_16x16x32_bf16(a, b0, acc0, 0, 0, 0);
        acc1 = __builtin_amdgcn_mfma_f32_16x16x32_bf16(a, b1, acc1, 0, 0, 0);
        acc2 = __builtin_amdgcn_mfma_f32_16x16x32_bf16(a, b2, acc2, 0, 0, 0);
    }

    const int cb = lane & 15;
    const int rr = rbase + (lane >> 4) * 4;
#pragma unroll
    for (int q = 0; q < 4; ++q) {
        int r = rr + q;
        if (r < NN) {
            z0[(size_t)r * 64 + cb] = f2bfu(acc0[q] + bc[cb]);
            z0[(size_t)r * 64 + cb + 16] = f2bfu(acc1[q] + bc[cb + 16]);
            z0[(size_t)r * 64 + cb + 32] = f2bfu(acc2[q] + bc[cb + 32]);
            z0[(size_t)r * 64 + cb + 48] = 0;
        }
    }
}

__global__ void count_kernel(const int* __restrict__ eidx, int* __restrict__ counts) {
    int e = blockIdx.x * 256 + threadIdx.x;
    if (e < EE) atomicAdd(&counts[eidx[EE + e]], 1);
}

__global__ void scan1(const int* __restrict__ counts, int* __restrict__ ptr,
                      int* __restrict__ bsum) {
    __shared__ int s[256];
    int tid = threadIdx.x;
    int i = blockIdx.x * 256 + tid;
    int v = (i < NN) ? counts[i] : 0;
    s[tid] = v;
    __syncthreads();
    for (int off = 1; off < 256; off <<= 1) {
        int t = (tid >= off) ? s[tid - off] : 0;
        __syncthreads();
        s[tid] += t;
        __syncthreads();
    }
    if (i < NN) ptr[i] = s[tid] - v;
    if (tid == 255) bsum[blockIdx.x] = s[255];
}

__global__ void scan2(int* __restrict__ bsum) {
    __shared__ int s[512];
    int tid = threadIdx.x;
    int v = (tid < 391) ? bsum[tid] : 0;
    s[tid] = v;
    __syncthreads();
    for (int off = 1; off < 512; off <<= 1) {
        int t = (tid >= off) ? s[tid - off] : 0;
        __syncthreads();
        s[tid] += t;
        __syncthreads();
    }
    if (tid < 391) bsum[tid] = s[tid] - v;
}

__global__ void scan3(int* __restrict__ ptr, const int* __restrict__ bsum,
                      const int* __restrict__ counts, float* __restrict__ dinvp,
                      int* __restrict__ ptr2) {
    int i = blockIdx.x * 256 + threadIdx.x;
    if (i < NN) {
        int p = ptr[i] + bsum[blockIdx.x];
        ptr[i] = p;
        ptr2[i] = p;
        dinvp[i] = rsqrtf(1.0f + (float)counts[i]);
    }
    if (i == 0) { ptr[NN] = EE; ptr2[NN] = EE; }
}

__global__ void scatter_kernel(const int* __restrict__ eidx,
                               const float* __restrict__ dinvp, int* __restrict__ ptr2,
                               int2* __restrict__ cev) {
    int e = blockIdx.x * 256 + threadIdx.x;
    if (e < EE) {
        int r = eidx[e];
        int c = eidx[EE + e];
        int pos = atomicAdd(&ptr2[c], 1);
        cev[pos] = make_int2(r, __float_as_int(dinvp[r]));
    }
}

// 2 nodes per wave; branch-free chunks of 8 edges per node, 16 gathers in flight.
// 32-bit gather offsets (uniform-base + voffset form); 8 waves/SIMD pinned.
__global__ __launch_bounds__(256, 8) void propagate(const unsigned short* __restrict__ zcur,
                                                    const unsigned short* __restrict__ z0q,
                                                    unsigned short* __restrict__ znb,
                                                    float* __restrict__ outf,
                                                    const int* __restrict__ ptr,
                                                    const int2* __restrict__ cev,
                                                    const float* __restrict__ dinvp,
                                                    const float* __restrict__ b2, int last) {
    const int lane = threadIdx.x & 63;
    const int wid = blockIdx.x * 4 + (threadIdx.x >> 6);
    const int n0 = wid, n1 = wid + HALFN;

    int beg0 = __builtin_amdgcn_readfirstlane(ptr[n0]);
    int end0 = __builtin_amdgcn_readfirstlane(ptr[n0 + 1]);
    int beg1 = __builtin_amdgcn_readfirstlane(ptr[n1]);
    int end1 = __builtin_amdgcn_readfirstlane(ptr[n1 + 1]);
    const float dc0 = dinvp[n0], dc1 = dinvp[n1];

    int m0 = end0 - beg0; if (m0 > 64) m0 = 64;
    int m1 = end1 - beg1; if (m1 > 64) m1 = 64;

    // batch loads: rows clamped to a valid entry, weights zeroed for lanes >= m
    int idx0 = beg0 + (lane < m0 ? lane : m0 - 1); if (idx0 < 0) idx0 = 0;
    int idx1 = beg1 + (lane < m1 ? lane : m1 - 1); if (idx1 < 0) idx1 = 0;
    int2 ev0 = cev[idx0];
    int2 ev1 = cev[idx1];
    if (lane >= m0) ev0.y = 0;
    if (lane >= m1) ev1.y = 0;

    const float self0 = bf2f(zcur[(unsigned)(n0 * 64 + lane)]);
    const float self1 = bf2f(zcur[(unsigned)(n1 * 64 + lane)]);
    const float z00 = bf2f(z0q[(unsigned)(n0 * 64 + lane)]);
    const float z01 = bf2f(z0q[(unsigned)(n1 * 64 + lane)]);

    float A0 = dc0 * self0, B0 = 0.f;
    float A1 = dc1 * self1, B1 = 0.f;

    int nc0 = (m0 + 7) >> 3, nc1 = (m1 + 7) >> 3;
    int nc = nc0 > nc1 ? nc0 : nc1;
    for (int c = 0; c < nc; ++c) {
        const int j = c * 8;
        float x[8], y[8];
#pragma unroll
        for (int k = 0; k < 8; ++k) {
            unsigned r0 = (unsigned)__builtin_amdgcn_readlane(ev0.x, j + k);
            unsigned r1 = (unsigned)__builtin_amdgcn_readlane(ev1.x, j + k);
            x[k] = bf2f(zcur[(r0 << 6) + lane]);
            y[k] = bf2f(zcur[(r1 << 6) + lane]);
        }
#pragma unroll
        for (int k = 0; k < 8; ++k) {
            float w = __int_as_float(__builtin_amdgcn_readlane(ev0.y, j + k));
            float u = __int_as_float(__builtin_amdgcn_readlane(ev1.y, j + k));
            if (k & 1) { B0 = fmaf(w, x[k], B0); B1 = fmaf(u, y[k], B1); }
            else       { A0 = fmaf(w, x[k], A0); A1 = fmaf(u, y[k], A1); }
        }
    }

    // ultra-rare tail: degree > 64
    for (int e = beg0 + 64; e < end0; ++e) {
        int2 ee = cev[e];
        A0 = fmaf(__int_as_float(ee.y), bf2f(zcur[((unsigned)ee.x << 6) + lane]), A0);
    }
    for (int e = beg1 + 64; e < end1; ++e) {
        int2 ee = cev[e];
        A1 = fmaf(__int_as_float(ee.y), bf2f(zcur[((unsigned)ee.x << 6) + lane]), A1);
    }

    float res0 = 0.5f * dc0 * (A0 + B0) + 0.5f * z00;
    float res1 = 0.5f * dc1 * (A1 + B1) + 0.5f * z01;
    if (last) {
        if (lane < 40) {
            outf[(unsigned)(n0 * 40 + lane)] = res0 + b2[lane];
            outf[(unsigned)(n1 * 40 + lane)] = res1 + b2[lane];
        }
    } else {
        znb[(unsigned)(n0 * 64 + lane)] = f2bfu(res0);
        znb[(unsigned)(n1 * 64 + lane)] = f2bfu(res1);
    }
}

extern "C" void kernel_launch(void* const* d_in, const int* in_sizes, int n_in,
                              void* d_out, int out_size, void* d_ws, size_t ws_size,
                              hipStream_t stream) {
    const float* x  = (const float*)d_in[0];
    const int*   ei = (const int*)d_in[1];
    const float* W1 = (const float*)d_in[2];
    const float* b1 = (const float*)d_in[3];
    const float* W2 = (const float*)d_in[4];
    const float* b2 = (const float*)d_in[5];
    float* out = (float*)d_out;

    char* ws = (char*)d_ws;
    short*          WcT  = (short*)(ws + 0);
    float*          bc   = (float*)(ws + 49152);
    unsigned short* z0   = (unsigned short*)(ws + 65536);
    unsigned short* za   = (unsigned short*)(ws + 12865536);
    unsigned short* zb   = (unsigned short*)(ws + 25665536);
    float*          dinv = (float*)(ws + 38465536);
    int*            cnt  = (int*)(ws + 38865536);
    int*            ptr  = (int*)(ws + 39265536);
    int*            bsum = (int*)(ws + 39665664);
    int*            ptr2 = (int*)(ws + 39667712);
    int2*           cev  = (int2*)(ws + 40067840);

    hipMemsetAsync(cnt, 0, NN * sizeof(int), stream);
    wct_kernel<<<97, 256, 0, stream>>>(W1, W2, b1, WcT, bc);
    count_kernel<<<(EE + 255) / 256, 256, 0, stream>>>(ei, cnt);
    scan1<<<391, 256, 0, stream>>>(cnt, ptr, bsum);
    scan2<<<1, 512, 0, stream>>>(bsum);
    scan3<<<391, 256, 0, stream>>>(ptr, bsum, cnt, dinv, ptr2);
    gemm_z0<<<1563, 256, 0, stream>>>(x, WcT, bc, z0);
    scatter_kernel<<<(EE + 255) / 256, 256, 0, stream>>>(ei, dinv, ptr2, cev);

    propagate<<<12500, 256, 0, stream>>>(z0, z0, zb, out, ptr, cev, dinv, b2, 0);
    propagate<<<12500, 256, 0, stream>>>(zb, z0, za, out, ptr, cev, dinv, b2, 0);
    propagate<<<12500, 256, 0, stream>>>(za, z0, zb, out, ptr, cev, dinv, b2, 0);
    propagate<<<12500, 256, 0, stream>>>(zb, z0, za, out, ptr, cev, dinv, b2, 0);
    propagate<<<12500, 256, 0, stream>>>(za, z0, zb, out, ptr, cev, dinv, b2, 1);
}